// Round 4
// baseline (810.794 us; speedup 1.0000x reference)
//
#include <hip/hip_runtime.h>
#include <hip/hip_bf16.h>

#define D_DIM 4096
#define RANK  819
#define RP    896      // rank padded to multiple of 128 (zero-filled)
#define MROWS 16384    // B*T = 8*2048

using floatx4 = __attribute__((ext_vector_type(4))) float;
using shortx8 = __attribute__((ext_vector_type(8))) short;

static __device__ __forceinline__ unsigned short f2bf(float f) {
  union { __hip_bfloat16 h; unsigned short u; } cv;
  cv.h = __float2bfloat16(f);
  return cv.u;
}

// UsT[r][d] = bf16(U[d][r] * S[r]) for r<RANK else 0.  UsT: [RP][D_DIM]
__global__ void prep_UsT(const float* __restrict__ U, const float* __restrict__ S,
                         unsigned short* __restrict__ UsT) {
  __shared__ float tile[32][33];
  const int r0 = blockIdx.x * 32;
  const int d0 = blockIdx.y * 32;
  const int tx = threadIdx.x, ty = threadIdx.y;
#pragma unroll
  for (int j = 0; j < 4; ++j) {
    const int d = d0 + ty + j * 8;
    const int r = r0 + tx;
    float v = 0.f;
    if (r < RANK) v = U[(size_t)d * RANK + r] * S[r];
    tile[ty + j * 8][tx] = v;
  }
  __syncthreads();
#pragma unroll
  for (int j = 0; j < 4; ++j) {
    const int r = r0 + ty + j * 8;
    const int d = d0 + tx;
    UsT[(size_t)r * D_DIM + d] = f2bf(tile[tx][ty + j * 8]);
  }
}

// VT[n][r] = bf16(V[r][n]) for r<RANK else 0.  VT: [D_DIM][RP]
__global__ void prep_VT(const float* __restrict__ V, unsigned short* __restrict__ VT) {
  __shared__ float tile[32][33];
  const int n0 = blockIdx.x * 32;
  const int r0 = blockIdx.y * 32;
  const int tx = threadIdx.x, ty = threadIdx.y;
#pragma unroll
  for (int j = 0; j < 4; ++j) {
    const int r = r0 + ty + j * 8;
    const int n = n0 + tx;
    float v = 0.f;
    if (r < RANK) v = V[(size_t)r * D_DIM + n];
    tile[ty + j * 8][tx] = v;
  }
  __syncthreads();
#pragma unroll
  for (int j = 0; j < 4; ++j) {
    const int n = n0 + ty + j * 8;
    const int r = r0 + tx;
    VT[(size_t)n * RP + r] = f2bf(tile[tx][ty + j * 8]);
  }
}

// C[M][N] = A[M][K] * B[K][N] (+ alpha*Xres), B given transposed: BT[N][K] bf16.
// 128x128 tile, BK=64, 256 threads (4 waves, 2x2), each wave 4x4 frags of 16x16x32.
template<bool A_F32, bool EPI, int KDIM, int LDA, int LDB, int LDC>
__global__ __launch_bounds__(256)
void gemm_k(const void* __restrict__ Aptr, const unsigned short* __restrict__ BT,
            void* __restrict__ Cptr, const float* __restrict__ Xres,
            const float* __restrict__ alpha_p)
{
  __shared__ unsigned short sA[128 * 64];
  __shared__ unsigned short sB[128 * 64];
  char* const sAb = (char*)sA;
  char* const sBb = (char*)sB;

  const int tid  = threadIdx.x;
  const int lane = tid & 63;
  const int wid  = tid >> 6;
  const int row0 = blockIdx.y * 128;
  const int col0 = blockIdx.x * 128;
  const int wm = (wid >> 1) * 64;
  const int wn = (wid & 1) * 64;

  floatx4 acc[4][4];
#pragma unroll
  for (int i = 0; i < 4; ++i)
#pragma unroll
    for (int j = 0; j < 4; ++j)
      acc[i][j] = floatx4{0.f, 0.f, 0.f, 0.f};

  const float* Af = (const float*)Aptr;
  const unsigned short* Ab = (const unsigned short*)Aptr;

  floatx4 raf[8];   // A staging regs (f32 path)
  shortx8 rab[4];   // A staging regs (bf16 path)
  shortx8 rb[4];    // B staging regs

  constexpr int NT = KDIM / 64;

  auto loadA = [&](int k0) {
    if constexpr (A_F32) {
#pragma unroll
      for (int i = 0; i < 8; ++i) {
        const int idx = i * 256 + tid;
        const int ar = idx >> 4, ac4 = idx & 15;          // 16 float4 per 64-col row
        raf[i] = *(const floatx4*)(Af + (size_t)(row0 + ar) * LDA + k0 + ac4 * 4);
      }
    } else {
#pragma unroll
      for (int i = 0; i < 4; ++i) {
        const int idx = i * 256 + tid;
        const int ar = idx >> 3, ac = idx & 7;            // 8 x 16B chunks per row
        rab[i] = *(const shortx8*)(Ab + (size_t)(row0 + ar) * LDA + k0 + ac * 8);
      }
    }
  };
  auto loadB = [&](int k0) {
#pragma unroll
    for (int i = 0; i < 4; ++i) {
      const int idx = i * 256 + tid;
      const int br = idx >> 3, bc = idx & 7;
      rb[i] = *(const shortx8*)(BT + (size_t)(col0 + br) * LDB + k0 + bc * 8);
    }
  };
  auto stage = [&]() {
    if constexpr (A_F32) {
#pragma unroll
      for (int i = 0; i < 8; ++i) {
        const int idx = i * 256 + tid;
        const int ar = idx >> 4, ac4 = idx & 15;
        const unsigned lo = ((unsigned)f2bf(raf[i].y) << 16) | f2bf(raf[i].x);
        const unsigned hi = ((unsigned)f2bf(raf[i].w) << 16) | f2bf(raf[i].z);
        const unsigned long long p = ((unsigned long long)hi << 32) | lo;
        const int off = ar * 128 + ((ac4 * 8) ^ ((ar & 7) << 4));   // T2 swizzle
        *(unsigned long long*)(sAb + off) = p;
      }
    } else {
#pragma unroll
      for (int i = 0; i < 4; ++i) {
        const int idx = i * 256 + tid;
        const int ar = idx >> 3, ac = idx & 7;
        const int off = ar * 128 + ((ac * 16) ^ ((ar & 7) << 4));
        *(shortx8*)(sAb + off) = rab[i];
      }
    }
#pragma unroll
    for (int i = 0; i < 4; ++i) {
      const int idx = i * 256 + tid;
      const int br = idx >> 3, bc = idx & 7;
      const int off = br * 128 + ((bc * 16) ^ ((br & 7) << 4));
      *(shortx8*)(sBb + off) = rb[i];
    }
  };

  loadA(0);
  loadB(0);

  for (int t = 0; t < NT; ++t) {
    stage();
    __syncthreads();
    if (t + 1 < NT) { loadA((t + 1) * 64); loadB((t + 1) * 64); }  // fly under MFMAs
#pragma unroll
    for (int ks = 0; ks < 2; ++ks) {
      shortx8 af[4], bfr[4];
      const int kb = ks * 4 + (lane >> 4);   // 16B chunk index along K
#pragma unroll
      for (int mi = 0; mi < 4; ++mi) {
        const int r = wm + mi * 16 + (lane & 15);
        af[mi] = *(const shortx8*)(sAb + r * 128 + ((kb * 16) ^ ((r & 7) << 4)));
      }
#pragma unroll
      for (int ni = 0; ni < 4; ++ni) {
        const int r = wn + ni * 16 + (lane & 15);
        bfr[ni] = *(const shortx8*)(sBb + r * 128 + ((kb * 16) ^ ((r & 7) << 4)));
      }
#pragma unroll
      for (int mi = 0; mi < 4; ++mi)
#pragma unroll
        for (int ni = 0; ni < 4; ++ni)
          acc[mi][ni] = __builtin_amdgcn_mfma_f32_16x16x32_bf16(af[mi], bfr[ni], acc[mi][ni], 0, 0, 0);
    }
    __syncthreads();
  }

  if constexpr (EPI) {
    const float alpha = *alpha_p;
    float* C = (float*)Cptr;
#pragma unroll
    for (int mi = 0; mi < 4; ++mi)
#pragma unroll
      for (int ni = 0; ni < 4; ++ni) {
        const int col = col0 + wn + ni * 16 + (lane & 15);
#pragma unroll
        for (int j = 0; j < 4; ++j) {
          const int row = row0 + wm + mi * 16 + ((lane >> 4) << 2) + j;
          const size_t o = (size_t)row * LDC + col;
          C[o] = acc[mi][ni][j] + alpha * Xres[o];
        }
      }
  } else {
    unsigned short* C = (unsigned short*)Cptr;
#pragma unroll
    for (int mi = 0; mi < 4; ++mi)
#pragma unroll
      for (int ni = 0; ni < 4; ++ni) {
        const int col = col0 + wn + ni * 16 + (lane & 15);
#pragma unroll
        for (int j = 0; j < 4; ++j) {
          const int row = row0 + wm + mi * 16 + ((lane >> 4) << 2) + j;
          C[(size_t)row * LDC + col] = f2bf(acc[mi][ni][j]);
        }
      }
  }
}

extern "C" void kernel_launch(void* const* d_in, const int* in_sizes, int n_in,
                              void* d_out, int out_size, void* d_ws, size_t ws_size,
                              hipStream_t stream) {
  const float* x     = (const float*)d_in[0];
  const float* U     = (const float*)d_in[1];
  const float* S     = (const float*)d_in[2];
  const float* V     = (const float*)d_in[3];
  const float* alpha = (const float*)d_in[4];

  unsigned short* UsT = (unsigned short*)d_ws;              // [RP][D_DIM] bf16
  unsigned short* VT  = UsT + (size_t)RP * D_DIM;           // [D_DIM][RP] bf16
  unsigned short* Y   = VT  + (size_t)D_DIM * RP;           // [MROWS][RP] bf16
  // ws use: (896*4096 + 4096*896 + 16384*896)*2 B = 42 MiB

  prep_UsT<<<dim3(RP / 32, D_DIM / 32), dim3(32, 8), 0, stream>>>(U, S, UsT);
  prep_VT <<<dim3(D_DIM / 32, RP / 32), dim3(32, 8), 0, stream>>>(V, VT);

  // GEMM1: Y[MROWS][RP] = x @ Us   (A f32 -> bf16 on stage; C bf16)
  gemm_k<true, false, D_DIM, D_DIM, D_DIM, RP>
      <<<dim3(RP / 128, MROWS / 128), 256, 0, stream>>>(x, UsT, Y, nullptr, nullptr);

  // GEMM2: out[MROWS][D_DIM] = Y @ V + alpha * x   (f32 out)
  gemm_k<false, true, RP, RP, RP, D_DIM>
      <<<dim3(D_DIM / 128, MROWS / 128), 256, 0, stream>>>(Y, VT, d_out, x, alpha);
}